// Round 13
// baseline (158.046 us; speedup 1.0000x reference)
//
#include <hip/hip_runtime.h>
#include <stdint.h>

constexpr int T_TOK = 8192;
constexpr int D_DIM = 1024;
constexpr int H_DIM = 2048;
constexpr int E_NUM = 8;

typedef __bf16 bf16x8 __attribute__((ext_vector_type(8)));
typedef float  f32x4  __attribute__((ext_vector_type(4)));
typedef unsigned int u32x4 __attribute__((ext_vector_type(4)));

static __device__ __forceinline__ unsigned short f2bf(float f) {
  union { float f; unsigned u; } a; a.f = f;
  unsigned r = a.u + 0x7fffu + ((a.u >> 16) & 1u);   // RNE
  return (unsigned short)(r >> 16);
}

// ---------------- fp32 -> bf16 conversion (x only) ----------------
__global__ void cvt_f32_bf16(const float* __restrict__ src,
                             unsigned short* __restrict__ dst, int n4) {
  int i = blockIdx.x * blockDim.x + threadIdx.x;
  int stride = gridDim.x * blockDim.x;
  for (; i < n4; i += stride) {
    float4 v = reinterpret_cast<const float4*>(src)[i];
    ushort4 o;
    o.x = f2bf(v.x); o.y = f2bf(v.y); o.z = f2bf(v.z); o.w = f2bf(v.w);
    reinterpret_cast<ushort4*>(dst)[i] = o;
  }
}

#define FENCE() asm volatile("" ::: "memory")
#define BARRIER() do { FENCE(); __builtin_amdgcn_s_barrier(); FENCE(); } while (0)
#define WAIT_LGKM0() asm volatile("s_waitcnt lgkmcnt(0)" ::: "memory")
#define WAIT_VM(N) asm volatile("s_waitcnt vmcnt(%0)" :: "i"(N) : "memory")
#define SCHED_FENCE() __builtin_amdgcn_sched_barrier(0)

static __device__ __forceinline__ f32x4 gload4(const void* p) {
  f32x4 r;
  asm volatile("global_load_dwordx4 %0, %1, off" : "=v"(r) : "v"(p) : "memory");
  return r;
}

// ============ GEMM1: fused w_up cvt (4-phase, BN=256) + RIDDEN w_down cvt ====
// Every vmem op (incl. the 2 cvt loads + 2 cvt stores per iter) sits in one
// per-wave FIFO; counted waits re-derived:
//   iter top: [bq0'(4), bq1'(4), S(2), L(2)] = 12
//   P1 +A(4)=16; P3 vm(12)->bq0', +nbq0; P4 vm(12)->bq1', +nbq1,
//   vm(8)->{S,L,A} (cvt data ready, A pre-barrier), +S'(2)+L'(2) -> 12.
// Prologue drains vm(0) once to enter the steady pattern uniformly.
// Chunks: block cwg=wg&255 converts float4[cwg*16384 .. +16384); chunk(it)
// clamped to NT-1 (tail duplicate = identical-byte store, benign).
__global__ __launch_bounds__(512, 2)
void gg1(const unsigned short* __restrict__ A,
         const float* __restrict__ Bw,
         const int* __restrict__ counts,
         unsigned short* __restrict__ Hout,
         const float* __restrict__ wdsrc,
         unsigned short* __restrict__ wddst) {
  constexpr int K_DIM = D_DIM, N_DIM = H_DIM;
  constexpr int BM = 256, BK = 64, BN = 256;
  constexpr int NT = K_DIM / BK;                 // 16
  constexpr int WNC = 64, NACC = 4, NQN = 2, BL = 4;
  constexpr int TOT4 = E_NUM * D_DIM * H_DIM / 4;   // 4,194,304 float4

  const int tid  = threadIdx.x;
  const int wid  = tid >> 6;
  const int lane = tid & 63;
  const int wr   = wid >> 2;
  const int wc   = wid & 3;

  // ---- XCD swizzle (grid 40x8 = 320, XCD = wg % 8)
  const int wg = blockIdx.x + gridDim.x * blockIdx.y;
  const int bx = wg >> 3;
  const int by = wg & 7;

  // ---- bx -> (expert, 256-row tile)
  int t = bx;
  int e = -1, rowBase = 0, rowsValid = 0;
  {
    int tiles = 0, off = 0;
#pragma unroll
    for (int i = 0; i < E_NUM; ++i) {
      int n  = counts[i];
      int nt = (n + BM - 1) / BM;
      if (e < 0 && t < tiles + nt) {
        e = i;
        int lt = t - tiles;
        rowBase   = off + lt * BM;
        rowsValid = n - lt * BM;
        if (rowsValid > BM) rowsValid = BM;
      }
      tiles += nt; off += n;
    }
  }

  const float4*  wds4 = reinterpret_cast<const float4*>(wdsrc);
  ushort4*       wdd4 = reinterpret_cast<ushort4*>(wddst);
  const int cwg    = wg & 255;
  const int cvBase = cwg * 16384 + tid * 2;       // float4 units

  if (e < 0) {
    // fallback (only reachable with skewed counts): convert own chunk plainly
    if (wg < 256) {
      for (int c = 0; c < NT; ++c) {
        int i0 = wg * 16384 + c * 1024 + tid * 2;
#pragma unroll
        for (int j = 0; j < 2; ++j) {
          if (i0 + j < TOT4) {
            float4 v = wds4[i0 + j];
            ushort4 o;
            o.x = f2bf(v.x); o.y = f2bf(v.y); o.z = f2bf(v.z); o.w = f2bf(v.w);
            wdd4[i0 + j] = o;
          }
        }
      }
    }
    return;
  }
  const int colBase = by * BN;

  __shared__ __align__(1024) char lds[(BM + BN) * BK * 2 * 2];  // 128 KiB
  auto ldsA = [&](int b) -> char* { return lds + b * (BM * 128); };
  auto ldsB = [&](int b) -> char* { return lds + 2 * (BM * 128) + b * (BN * 128); };

  const char* gA = (const char*)A + (size_t)rowBase * (K_DIM * 2);
  const int  bRow0 = tid >> 2;
  const int  bByte = (tid & 3) * 64;
  const char* gBbase = (const char*)Bw +
      ((size_t)e * N_DIM + colBase) * (size_t)(K_DIM * 4);

  const int lr8 = lane >> 3;
  const int gsw = (lane & 7) ^ lr8;    // inverse-swizzled source granule (A)

  auto stageA = [&](int buf, int alpha, int kt) {
#pragma unroll
    for (int j = 0; j < 2; ++j) {
      int bi   = j * 8 + wid;
      int row0 = (bi >> 3) * 128 + alpha * 64 + (bi & 7) * 8;
      int sr   = row0 + lr8;
      if (sr >= rowsValid) sr = rowsValid - 1;
      const char* src = gA + (size_t)sr * (K_DIM * 2) + (size_t)kt * 128 + gsw * 16;
      __builtin_amdgcn_global_load_lds(
          (const __attribute__((address_space(1))) void*)src,
          (__attribute__((address_space(3))) void*)(ldsA(buf) + row0 * 128),
          16, 0, 0);
    }
  };

  auto loadBhalf = [&](f32x4 (&q)[BL], int h, int kt) {
    const char* s = gBbase + (size_t)(h * (BN / 2) + bRow0) * (K_DIM * 4)
                  + (size_t)kt * 256 + bByte;
#pragma unroll
    for (int j = 0; j < BL; ++j) q[j] = gload4(s + j * 16);
  };
  auto writeBhalf = [&](int buf, const f32x4 (&q)[BL], int h) {
    const int row = h * (BN / 2) + bRow0;
    char* base = ldsB(buf) + row * 128;
    const int rs = row & 7;
#pragma unroll
    for (int c = 0; c < BL / 2; ++c) {
      union { __bf16 b[8]; u32x4 w; } u;
#pragma unroll
      for (int k = 0; k < 2; ++k)
#pragma unroll
        for (int p = 0; p < 4; ++p)
          u.b[k * 4 + p] = (__bf16)q[c * 2 + k][p];
      int g = 2 * (tid & 3) + c;
      *reinterpret_cast<u32x4*>(base + (g ^ rs) * 16) = u.w;
    }
  };

  // ---- ridden w_down convert (2 float4 per thread per chunk)
  auto loadCv = [&](f32x4 (&L)[2], int c) {
    int cc = c < NT ? c : NT - 1;
    const char* p = (const char*)(wds4 + cvBase + cc * 1024);
    L[0] = gload4(p);
    L[1] = gload4(p + 16);
  };
  auto cvtStoreCv = [&](const f32x4 (&L)[2], int c) {
    int cc = c < NT ? c : NT - 1;
    ushort4* q = wdd4 + cvBase + cc * 1024;
#pragma unroll
    for (int j = 0; j < 2; ++j) {
      union { __bf16 b[4]; ushort4 u; } w;
#pragma unroll
      for (int p = 0; p < 4; ++p) w.b[p] = (__bf16)L[j][p];
      q[j] = w.u;                                  // global_store (counts in vmcnt)
    }
  };

  const int rowLane = lane & 15;
  const int grpA    = lane >> 4;
  const int swzm    = lane & 7;

  bf16x8 aF[4][2];
  f32x4  accC[8][NACC];
#pragma unroll
  for (int m = 0; m < 8; ++m)
#pragma unroll
    for (int n = 0; n < NACC; ++n) accC[m][n] = (f32x4){0.f, 0.f, 0.f, 0.f};

  auto readA = [&](int buf, int rh) {
    const char* base = ldsA(buf) + (wr * 128 + rh * 64 + rowLane) * 128;
#pragma unroll
    for (int m = 0; m < 4; ++m)
#pragma unroll
      for (int ks = 0; ks < 2; ++ks) {
        int g = (ks * 4 + grpA) ^ swzm;
        aF[m][ks] = *(const bf16x8*)(base + m * (16 * 128) + g * 16);
      }
  };
  bf16x8 bF0[NQN][2], bF1[NQN][2];
  auto readB = [&](int buf, int ch, bf16x8 (&dst)[NQN][2]) {
    const char* base = ldsB(buf) + (wc * WNC + ch * (WNC / 2) + rowLane) * 128;
#pragma unroll
    for (int n = 0; n < NQN; ++n)
#pragma unroll
      for (int ks = 0; ks < 2; ++ks) {
        int g = (ks * 4 + grpA) ^ swzm;
        dst[n][ks] = *(const bf16x8*)(base + n * (16 * 128) + g * 16);
      }
  };

#define MFMAQ(RH, CH, BFA)                                                    \
  do {                                                                        \
    __builtin_amdgcn_s_setprio(1);                                            \
    _Pragma("unroll")                                                         \
    for (int m_ = 0; m_ < 4; ++m_) {                                          \
      _Pragma("unroll")                                                       \
      for (int n_ = 0; n_ < NQN; ++n_) {                                      \
        f32x4 c_ = accC[(RH) * 4 + m_][(CH) * NQN + n_];                      \
        c_ = __builtin_amdgcn_mfma_f32_16x16x32_bf16(aF[m_][0], BFA[n_][0], c_, 0, 0, 0); \
        c_ = __builtin_amdgcn_mfma_f32_16x16x32_bf16(aF[m_][1], BFA[n_][1], c_, 0, 0, 0); \
        accC[(RH) * 4 + m_][(CH) * NQN + n_] = c_;                            \
      }                                                                       \
    }                                                                         \
    __builtin_amdgcn_s_setprio(0);                                            \
  } while (0)

  f32x4 bq0[BL], bq1[BL], cvL[2];

  // ---- prologue: tile0 -> buf0; tile1 B in flight; cvt chunk0 done here
  loadBhalf(bq0, 0, 0);
  loadBhalf(bq1, 1, 0);
  stageA(0, 0, 0); stageA(0, 1, 0);
  WAIT_VM(8); SCHED_FENCE();
  writeBhalf(0, bq0, 0);
  loadBhalf(bq0, 0, 1);
  WAIT_VM(8); SCHED_FENCE();
  writeBhalf(0, bq1, 1);
  loadBhalf(bq1, 1, 1);
  WAIT_VM(8);                      // drains A stages
  loadCv(cvL, 0);
  WAIT_VM(0); SCHED_FENCE();       // full drain once (enters uniform pattern)
  cvtStoreCv(cvL, 0);              // +2 stores
  loadCv(cvL, 1);                  // +2 loads  -> outstanding [S2, L2]
  WAIT_LGKM0();
  BARRIER();

  for (int t2 = 0; t2 < NT; ++t2) {
    const int cur = t2 & 1, nxt = cur ^ 1;
    const int ktn  = (t2 + 1 < NT) ? t2 + 1 : NT - 1;
    const int ktn2 = (t2 + 2 < NT) ? t2 + 2 : NT - 1;

    // P1
    stageA(nxt, 0, ktn);
    stageA(nxt, 1, ktn);
    readA(cur, 0); readB(cur, 0, bF0);
    BARRIER(); WAIT_LGKM0();
    MFMAQ(0, 0, bF0);
    BARRIER();
    // P2
    readB(cur, 1, bF1);
    BARRIER(); WAIT_LGKM0();
    MFMAQ(0, 1, bF1);
    BARRIER();
    // P3: drain bq0 (keep bq1 4 + S 2 + L 2 + A 4 = 12)
    WAIT_VM(12);
    SCHED_FENCE();
    writeBhalf(nxt, bq0, 0);
    loadBhalf(bq0, 0, ktn2);
    readA(cur, 1);
    BARRIER(); WAIT_LGKM0();
    MFMAQ(1, 1, bF1);
    BARRIER();
    // P4: drain bq1 (keep S+L+A+nbq0 = 12); then drain S,L,A (keep nbq 8);
    //     convert ridden chunk, store, load next chunk
    WAIT_VM(12);
    SCHED_FENCE();
    writeBhalf(nxt, bq1, 1);
    loadBhalf(bq1, 1, ktn2);
    WAIT_VM(8);
    SCHED_FENCE();
    cvtStoreCv(cvL, t2 + 1);
    loadCv(cvL, t2 + 2);
    BARRIER(); WAIT_LGKM0();
    MFMAQ(1, 0, bF0);
    BARRIER();
  }
#undef MFMAQ

  // ---- drain never-consumed final loads; keep dest regs alive (r6 lesson)
  WAIT_VM(0);
  SCHED_FENCE();
#pragma unroll
  for (int j = 0; j < BL; ++j) {
    asm volatile("" :: "v"(bq0[j]), "v"(bq1[j]));
  }
  asm volatile("" :: "v"(cvL[0]), "v"(cvL[1]));

  // ---- epilogue: h = bf16(bf16(relu(acc))^2)
  const int rB0 = wr * 128 + grpA * 4;
  const int cB0 = colBase + wc * WNC + rowLane;
#pragma unroll
  for (int m = 0; m < 8; ++m) {
#pragma unroll
    for (int n = 0; n < NACC; ++n) {
#pragma unroll
      for (int j = 0; j < 4; ++j) {
        int r = rB0 + m * 16 + j;
        if (r < rowsValid) {
          size_t idx = (size_t)(rowBase + r) * N_DIM + (cB0 + n * 16);
          float v = accC[m][n][j];
          float rl = v > 0.f ? v : 0.f;
          float hf = (float)(__bf16)rl;
          ((__bf16*)Hout)[idx] = (__bf16)(hf * hf);
        }
      }
    }
  }
}

// ============ GEMM2: clean bf16 B (gload_lds 8-phase, BN=128) + swizzle ======
template <int K_DIM, int N_DIM>
__global__ __launch_bounds__(512, 2)
void gg2(const unsigned short* __restrict__ A,
         const unsigned short* __restrict__ Bw,
         const int* __restrict__ counts,
         float* __restrict__ Cout) {
  constexpr int BM = 256, BK = 64, BN = 128;
  constexpr int NT = K_DIM / BK;
  constexpr int NITER = NT / 2;
  constexpr int WNC = 32, VN = 5;

  const int tid  = threadIdx.x;
  const int wid  = tid >> 6;
  const int lane = tid & 63;
  const int wr   = wid >> 2;
  const int wc   = wid & 3;

  const int wg = blockIdx.x + gridDim.x * blockIdx.y;   // grid 40 x 8
  const int bx = wg >> 3;
  const int by = wg & 7;

  int t = bx;
  int e = -1, rowBase = 0, rowsValid = 0;
  {
    int tiles = 0, off = 0;
#pragma unroll
    for (int i = 0; i < E_NUM; ++i) {
      int n  = counts[i];
      int nt = (n + BM - 1) / BM;
      if (e < 0 && t < tiles + nt) {
        e = i;
        int lt = t - tiles;
        rowBase   = off + lt * BM;
        rowsValid = n - lt * BM;
        if (rowsValid > BM) rowsValid = BM;
      }
      tiles += nt; off += n;
    }
  }
  if (e < 0) return;
  const int colBase = by * BN;

  __shared__ __align__(1024) char lds[(BM + BN) * BK * 2 * 2];  // 96 KiB
  auto ldsA = [&](int b) -> char* { return lds + b * (BM * 128); };
  auto ldsB = [&](int b) -> char* { return lds + 2 * (BM * 128) + b * (BN * 128); };

  const char* gA = (const char*)A + (size_t)rowBase * (K_DIM * 2);
  const char* gB = (const char*)Bw + ((size_t)e * N_DIM + colBase) * (size_t)(K_DIM * 2);

  const int lr8 = lane >> 3;
  const int gsw = (lane & 7) ^ lr8;

  auto stageA = [&](int buf, int alpha, int kt) {
#pragma unroll
    for (int j = 0; j < 2; ++j) {
      int bi   = j * 8 + wid;
      int row0 = (bi >> 3) * 128 + alpha * 64 + (bi & 7) * 8;
      int sr   = row0 + lr8;
      if (sr >= rowsValid) sr = rowsValid - 1;
      const char* src = gA + (size_t)sr * (K_DIM * 2) + (size_t)kt * 128 + gsw * 16;
      __builtin_amdgcn_global_load_lds(
          (const __attribute__((address_space(1))) void*)src,
          (__attribute__((address_space(3))) void*)(ldsA(buf) + row0 * 128),
          16, 0, 0);
    }
  };
  auto stageB = [&](int buf, int alpha, int kt) {
    int bi   = wid;
    int row0 = (bi >> 1) * 32 + alpha * 16 + (bi & 1) * 8;
    int sr   = row0 + lr8;
    const char* src = gB + (size_t)sr * (K_DIM * 2) + (size_t)kt * 128 + gsw * 16;
    __builtin_amdgcn_global_load_lds(
        (const __attribute__((address_space(1))) void*)src,
        (__attribute__((address_space(3))) void*)(ldsB(buf) + row0 * 128),
        16, 0, 0);
  };

  const int rowLane = lane & 15;
  const int grpA    = lane >> 4;
  const int swzm    = lane & 7;

  bf16x8 aF[4][2];
  bf16x8 bF0[2], bF1[2];
  f32x4  accC[8][2];
#pragma unroll
  for (int m = 0; m < 8; ++m)
#pragma unroll
    for (int n = 0; n < 2; ++n) accC[m][n] = (f32x4){0.f, 0.f, 0.f, 0.f};

  auto readA = [&](int buf, int rh) {
    const char* base = ldsA(buf) + (wr * 128 + rh * 64 + rowLane) * 128;
#pragma unroll
    for (int m = 0; m < 4; ++m)
#pragma unroll
      for (int ks = 0; ks < 2; ++ks) {
        int g = (ks * 4 + grpA) ^ swzm;
        aF[m][ks] = *(const bf16x8*)(base + m * (16 * 128) + g * 16);
      }
  };
  auto readB = [&](int buf, int ch, bf16x8 (&dst)[2]) {
    const char* base = ldsB(buf) + (wc * WNC + ch * 16 + rowLane) * 128;
#pragma unroll
    for (int ks = 0; ks < 2; ++ks) {
      int g = (ks * 4 + grpA) ^ swzm;
      dst[ks] = *(const bf16x8*)(base + g * 16);
    }
  };

#define MFMAQ2(RH, CH, BFA)                                                   \
  do {                                                                        \
    __builtin_amdgcn_s_setprio(1);                                            \
    _Pragma("unroll")                                                         \
    for (int m_ = 0; m_ < 4; ++m_) {                                          \
      f32x4 c_ = accC[(RH) * 4 + m_][(CH)];                                   \
      c_ = __builtin_amdgcn_mfma_f32_16x16x32_bf16(aF[m_][0], BFA[0], c_, 0, 0, 0); \
      c_ = __builtin_amdgcn_mfma_f32_16x16x32_bf16(aF[m_][1], BFA[1], c_, 0, 0, 0); \
      accC[(RH) * 4 + m_][(CH)] = c_;                                         \
    }                                                                         \
    __builtin_amdgcn_s_setprio(0);                                            \
  } while (0)

  // ---- prologue: tile0 {A0,B0,A1,B1} + tile1 {A0,B0,A1}; B1(tile1) at P1.
  stageA(0, 0, 0); stageB(0, 0, 0); stageA(0, 1, 0); stageB(0, 1, 0);
  stageA(1, 0, 1); stageB(1, 0, 1); stageA(1, 1, 1);
  WAIT_VM(VN);
  BARRIER();

  for (int it = 0; it < NITER; ++it) {
    const int t0  = 2 * it;
    const int kB1 = t0 + 1;
    const int kN0 = (t0 + 2 < NT) ? t0 + 2 : NT - 1;
    const int kN1 = (t0 + 3 < NT) ? t0 + 3 : NT - 1;

    // P1
    readA(0, 0); readB(0, 0, bF0);
    stageB(1, 1, kB1);
    BARRIER(); WAIT_LGKM0();
    MFMAQ2(0, 0, bF0);
    BARRIER();
    // P2
    readB(0, 1, bF1);
    stageA(0, 0, kN0);
    BARRIER(); WAIT_LGKM0();
    MFMAQ2(0, 1, bF1);
    BARRIER();
    // P3
    readA(0, 1);
    stageB(0, 0, kN0);
    BARRIER(); WAIT_LGKM0();
    MFMAQ2(1, 1, bF1);
    BARRIER();
    // P4
    stageA(0, 1, kN0);
    WAIT_VM(VN);
    BARRIER();
    MFMAQ2(1, 0, bF0);
    BARRIER();
    // P5
    readA(1, 0); readB(1, 0, bF0);
    stageB(0, 1, kN0);
    BARRIER(); WAIT_LGKM0();
    MFMAQ2(0, 0, bF0);
    BARRIER();
    // P6
    readB(1, 1, bF1);
    stageA(1, 0, kN1);
    BARRIER(); WAIT_LGKM0();
    MFMAQ2(0, 1, bF1);
    BARRIER();
    // P7
    readA(1, 1);
    stageB(1, 0, kN1);
    BARRIER(); WAIT_LGKM0();
    MFMAQ2(1, 1, bF1);
    BARRIER();
    // P8
    stageA(1, 1, kN1);
    WAIT_VM(VN);
    BARRIER();
    MFMAQ2(1, 0, bF0);
    BARRIER();
  }
#undef MFMAQ2

  // ---- epilogue: out = float(bf16(acc))
  const int rB0 = wr * 128 + grpA * 4;
  const int cB0 = colBase + wc * WNC + rowLane;
#pragma unroll
  for (int m = 0; m < 8; ++m) {
#pragma unroll
    for (int n = 0; n < 2; ++n) {
#pragma unroll
      for (int j = 0; j < 4; ++j) {
        int r = rB0 + m * 16 + j;
        if (r < rowsValid) {
          size_t idx = (size_t)(rowBase + r) * N_DIM + (cB0 + n * 16);
          Cout[idx] = (float)(__bf16)accC[m][n][j];
        }
      }
    }
  }
}

extern "C" void kernel_launch(void* const* d_in, const int* in_sizes, int n_in,
                              void* d_out, int out_size, void* d_ws, size_t ws_size,
                              hipStream_t stream) {
  const float* x   = (const float*)d_in[0];
  const int*   cnt = (const int*)d_in[1];
  const float* wu  = (const float*)d_in[2];
  const float* wd  = (const float*)d_in[3];
  float* out = (float*)d_out;
  char*  ws  = (char*)d_ws;

  unsigned short* xb   = (unsigned short*)(ws);                // 16 MiB
  unsigned short* hbuf = (unsigned short*)(ws + (16u << 20));  // 32 MiB
  unsigned short* wdb  = (unsigned short*)(ws + (48u << 20));  // 32 MiB

  cvt_f32_bf16<<<2048, 256, 0, stream>>>(x, xb, T_TOK * D_DIM / 4);

  // GEMM1 (fused w_up cvt) with ridden w_down convert; grid 40x8 = 320
  gg1<<<dim3(40, H_DIM / 256), dim3(512), 0, stream>>>(
      xb, wu, cnt, hbuf, wd, wdb);

  // GEMM2: clean bf16 B from wdb (round-2-proven 8-phase path)
  gg2<H_DIM, D_DIM><<<dim3(40, D_DIM / 128), dim3(512), 0, stream>>>(
      hbuf, wdb, cnt, out);
}

// Round 14
// 121.976 us; speedup vs baseline: 1.2957x; 1.2957x over previous
//
#include <hip/hip_runtime.h>
#include <stdint.h>

constexpr int T_TOK = 8192;
constexpr int D_DIM = 1024;
constexpr int H_DIM = 2048;
constexpr int E_NUM = 8;

typedef __bf16 bf16x8 __attribute__((ext_vector_type(8)));
typedef float  f32x4  __attribute__((ext_vector_type(4)));

static __device__ __forceinline__ unsigned short f2bf(float f) {
  union { float f; unsigned u; } a; a.f = f;
  unsigned r = a.u + 0x7fffu + ((a.u >> 16) & 1u);   // RNE
  return (unsigned short)(r >> 16);
}

// ---------------- fp32 -> bf16 conversion (x only) ----------------
__global__ void cvt_f32_bf16(const float* __restrict__ src,
                             unsigned short* __restrict__ dst, int n4) {
  int i = blockIdx.x * blockDim.x + threadIdx.x;
  int stride = gridDim.x * blockDim.x;
  for (; i < n4; i += stride) {
    float4 v = reinterpret_cast<const float4*>(src)[i];
    ushort4 o;
    o.x = f2bf(v.x); o.y = f2bf(v.y); o.z = f2bf(v.z); o.w = f2bf(v.w);
    reinterpret_cast<ushort4*>(dst)[i] = o;
  }
}

#define FENCE() asm volatile("" ::: "memory")
#define BARRIER() do { FENCE(); __builtin_amdgcn_s_barrier(); FENCE(); } while (0)
#define WAIT_LGKM0() asm volatile("s_waitcnt lgkmcnt(0)" ::: "memory")
#define WAIT_VM(N) asm volatile("s_waitcnt vmcnt(%0)" :: "i"(N) : "memory")

// ==== grouped GEMM, B fp32 staged via global_load_lds, cvt-on-LDS-read ====
// BM=256, BN=128, BK=64, 8 waves. Schedule = round-2-proven 8-phase with
// counted vmcnt ONLY at P4/P8 (VN=6: stageA=2 issues, stageB=2 issues).
// B LDS is fp32 [128 rows][256B]: 16-granule XOR swizzle (g ^= row&15),
// applied as pre-swizzled GLOBAL source (gload_lds dest is linear) and the
// same XOR on the read side (both-sides rule #21). Fragment read = 2x
// ds_read_b128 (independent granules) -> v_cvt_pk_bf16_f32 on read.
// FIFO ledger (enumerated, steady state): P8-wait leaves [P6,P7,P8]=6;
// P4-wait drains {P6p,P7p,P8p,P1} before P5's buf1 reads; P8-wait drains
// {P2,P3,P4,P5} before next-P1's buf0 reads. Prologue leaves tile-1's 6.
template <int K_DIM, int N_DIM, bool RELU2>
__global__ __launch_bounds__(512, 2)
void ggf(const unsigned short* __restrict__ A,
         const float* __restrict__ Bw,
         const int* __restrict__ counts,
         void* __restrict__ Cout) {
  constexpr int BM = 256, BK = 64, BN = 128;
  constexpr int NT = K_DIM / BK;
  constexpr int NITER = NT / 2;
  constexpr int NCOLT = N_DIM / BN;     // 16 (GEMM1) or 8 (GEMM2)
  constexpr int VN = 6;

  const int tid  = threadIdx.x;
  const int wid  = tid >> 6;
  const int lane = tid & 63;
  const int wr   = wid >> 2;            // 0..1
  const int wc   = wid & 3;             // 0..3

  // ---- XCD swizzle: hardware XCD = linear wg % 8; pin col-tiles per XCD
  const int id = blockIdx.x + gridDim.x * blockIdx.y;
  int ct, rt;
  if (NCOLT == 16) { ct = (id & 7) | (((id >> 3) & 1) << 3); rt = id >> 4; }
  else             { ct = id & 7;                            rt = id >> 3; }

  // ---- rt -> (expert, 256-row tile)
  int t = rt;
  int e = -1, rowBase = 0, rowsValid = 0;
  {
    int tiles = 0, off = 0;
#pragma unroll
    for (int i = 0; i < E_NUM; ++i) {
      int n  = counts[i];
      int nt = (n + BM - 1) / BM;
      if (e < 0 && t < tiles + nt) {
        e = i;
        int lt = t - tiles;
        rowBase   = off + lt * BM;
        rowsValid = n - lt * BM;
        if (rowsValid > BM) rowsValid = BM;
      }
      tiles += nt; off += n;
    }
  }
  if (e < 0) return;
  const int colBase = ct * BN;

  // LDS: A bf16 dbuf 64 KiB + B fp32 dbuf 64 KiB = 128 KiB
  __shared__ __align__(1024) char lds[2 * BM * 128 + 2 * BN * 256];
  auto ldsA = [&](int b) -> char* { return lds + b * (BM * 128); };
  auto ldsB = [&](int b) -> char* { return lds + 2 * (BM * 128) + b * (BN * 256); };

  const char* gA = (const char*)A + (size_t)rowBase * (K_DIM * 2);
  const char* gB = (const char*)Bw + ((size_t)e * N_DIM + colBase) * (size_t)(K_DIM * 4);

  const int lr8 = lane >> 3;
  const int gswA = (lane & 7) ^ lr8;    // A: 8-granule inverse source swizzle

  auto stageA = [&](int buf, int alpha, int kt) {
#pragma unroll
    for (int j = 0; j < 2; ++j) {
      int bi   = j * 8 + wid;
      int row0 = (bi >> 3) * 128 + alpha * 64 + (bi & 7) * 8;
      int sr   = row0 + lr8;
      if (sr >= rowsValid) sr = rowsValid - 1;
      const char* src = gA + (size_t)sr * (K_DIM * 2) + (size_t)kt * 128 + gswA * 16;
      __builtin_amdgcn_global_load_lds(
          (const __attribute__((address_space(1))) void*)src,
          (__attribute__((address_space(3))) void*)(ldsA(buf) + row0 * 128),
          16, 0, 0);
    }
  };

  // B fp32 staging: half-tile (64 rows x 256B) = 2 issues of 8KB.
  // Wave covers 4 rows/issue; lane: row = row0u + (lane>>4), dest linear,
  // source granule pre-swizzled by row&15.
  auto stageB = [&](int buf, int alpha, int kt) {
#pragma unroll
    for (int j = 0; j < 2; ++j) {
      int row0u = alpha * 64 + j * 32 + wid * 4;          // wave-uniform
      int row   = row0u + (lane >> 4);
      int srcg  = (lane & 15) ^ (row & 15);
      const char* src = gB + (size_t)row * (K_DIM * 4) + (size_t)kt * 256 + srcg * 16;
      __builtin_amdgcn_global_load_lds(
          (const __attribute__((address_space(1))) void*)src,
          (__attribute__((address_space(3))) void*)(ldsB(buf) + row0u * 256),
          16, 0, 0);
    }
  };

  const int rowLane = lane & 15;
  const int grpA    = lane >> 4;
  const int swzmA   = lane & 7;

  bf16x8 aF[4][2];
  bf16x8 bF0[2], bF1[2];
  f32x4  accC[8][2];
#pragma unroll
  for (int m = 0; m < 8; ++m)
#pragma unroll
    for (int n = 0; n < 2; ++n) accC[m][n] = (f32x4){0.f, 0.f, 0.f, 0.f};

  auto readA = [&](int buf, int rh) {
    const char* base = ldsA(buf) + (wr * 128 + rh * 64 + rowLane) * 128;
#pragma unroll
    for (int m = 0; m < 4; ++m)
#pragma unroll
      for (int ks = 0; ks < 2; ++ks) {
        int g = (ks * 4 + grpA) ^ swzmA;
        aF[m][ks] = *(const bf16x8*)(base + m * (16 * 128) + g * 16);
      }
  };
  // read B col-frag ch: rows wc*32+ch*16+rowLane; granules (ks*8+grpA*2+c)^rowLane;
  // cvt fp32->bf16 on read (compiler emits v_cvt_pk_bf16_f32).
  auto readB = [&](int buf, int ch, bf16x8 (&dst)[2]) {
    const char* base = ldsB(buf) + (wc * 32 + ch * 16 + rowLane) * 256;
#pragma unroll
    for (int ks = 0; ks < 2; ++ks) {
      f32x4 v0 = *(const f32x4*)(base + (((ks * 8 + grpA * 2 + 0) ^ rowLane) * 16));
      f32x4 v1 = *(const f32x4*)(base + (((ks * 8 + grpA * 2 + 1) ^ rowLane) * 16));
      union { __bf16 b[8]; bf16x8 v; } u;
#pragma unroll
      for (int p = 0; p < 4; ++p) {
        u.b[p]     = (__bf16)v0[p];
        u.b[4 + p] = (__bf16)v1[p];
      }
      dst[ks] = u.v;
    }
  };

#define MFMAQ2(RH, CH, BFA)                                                   \
  do {                                                                        \
    __builtin_amdgcn_s_setprio(1);                                            \
    _Pragma("unroll")                                                         \
    for (int m_ = 0; m_ < 4; ++m_) {                                          \
      f32x4 c_ = accC[(RH) * 4 + m_][(CH)];                                   \
      c_ = __builtin_amdgcn_mfma_f32_16x16x32_bf16(aF[m_][0], BFA[0], c_, 0, 0, 0); \
      c_ = __builtin_amdgcn_mfma_f32_16x16x32_bf16(aF[m_][1], BFA[1], c_, 0, 0, 0); \
      accC[(RH) * 4 + m_][(CH)] = c_;                                         \
    }                                                                         \
    __builtin_amdgcn_s_setprio(0);                                            \
  } while (0)

  // ---- prologue: tile0 {A0,B0,A1,B1} + tile1 {A0,B0,A1}; B1(tile1) at P1.
  stageA(0, 0, 0); stageB(0, 0, 0); stageA(0, 1, 0); stageB(0, 1, 0);
  stageA(1, 0, 1); stageB(1, 0, 1); stageA(1, 1, 1);
  WAIT_VM(VN);        // drains tile0's 8 issues; leaves tile1's 6
  BARRIER();

  for (int it = 0; it < NITER; ++it) {
    const int t0  = 2 * it;
    const int kB1 = t0 + 1;
    const int kN0 = (t0 + 2 < NT) ? t0 + 2 : NT - 1;   // tail re-stage benign
    const int kN1 = (t0 + 3 < NT) ? t0 + 3 : NT - 1;

    // P1
    readA(0, 0); readB(0, 0, bF0);
    stageB(1, 1, kB1);
    BARRIER(); WAIT_LGKM0();
    MFMAQ2(0, 0, bF0);
    BARRIER();
    // P2
    readB(0, 1, bF1);
    stageA(0, 0, kN0);
    BARRIER(); WAIT_LGKM0();
    MFMAQ2(0, 1, bF1);
    BARRIER();
    // P3
    readA(0, 1);
    stageB(0, 0, kN0);
    BARRIER(); WAIT_LGKM0();
    MFMAQ2(1, 1, bF1);
    BARRIER();
    // P4
    stageA(0, 1, kN0);
    WAIT_VM(VN);
    BARRIER();
    MFMAQ2(1, 0, bF0);
    BARRIER();
    // P5
    readA(1, 0); readB(1, 0, bF0);
    stageB(0, 1, kN0);
    BARRIER(); WAIT_LGKM0();
    MFMAQ2(0, 0, bF0);
    BARRIER();
    // P6
    readB(1, 1, bF1);
    stageA(1, 0, kN1);
    BARRIER(); WAIT_LGKM0();
    MFMAQ2(0, 1, bF1);
    BARRIER();
    // P7
    readA(1, 1);
    stageB(1, 0, kN1);
    BARRIER(); WAIT_LGKM0();
    MFMAQ2(1, 1, bF1);
    BARRIER();
    // P8
    stageA(1, 1, kN1);
    WAIT_VM(VN);
    BARRIER();
    MFMAQ2(1, 0, bF0);
    BARRIER();
  }
#undef MFMAQ2

  // ---- epilogue. C/D: col = lane&15, row = (lane>>4)*4 + j
  const int rB0 = wr * 128 + grpA * 4;
  const int cB0 = colBase + wc * 32 + rowLane;
#pragma unroll
  for (int m = 0; m < 8; ++m) {
#pragma unroll
    for (int n = 0; n < 2; ++n) {
#pragma unroll
      for (int j = 0; j < 4; ++j) {
        int r = rB0 + m * 16 + j;
        if (r < rowsValid) {
          size_t idx = (size_t)(rowBase + r) * N_DIM + (cB0 + n * 16);
          float v = accC[m][n][j];
          if (RELU2) {
            float rl = v > 0.f ? v : 0.f;
            float hf = (float)(__bf16)rl;              // bf16(relu(acc))
            ((__bf16*)Cout)[idx] = (__bf16)(hf * hf);  // bf16 square
          } else {
            ((float*)Cout)[idx] = (float)(__bf16)v;    // float(bf16(acc))
          }
        }
      }
    }
  }
}

extern "C" void kernel_launch(void* const* d_in, const int* in_sizes, int n_in,
                              void* d_out, int out_size, void* d_ws, size_t ws_size,
                              hipStream_t stream) {
  const float* x   = (const float*)d_in[0];
  const int*   cnt = (const int*)d_in[1];
  const float* wu  = (const float*)d_in[2];
  const float* wd  = (const float*)d_in[3];
  float* out = (float*)d_out;
  char*  ws  = (char*)d_ws;

  unsigned short* xb   = (unsigned short*)(ws);                // 16 MiB
  unsigned short* hbuf = (unsigned short*)(ws + (16u << 20));  // 32 MiB

  cvt_f32_bf16<<<2048, 256, 0, stream>>>(x, xb, T_TOK * D_DIM / 4);

  // GEMM1: h = bf16(bf16(relu(x@wu^T))^2); grid 40 x 16 = 640
  ggf<D_DIM, H_DIM, true ><<<dim3(40, H_DIM / 128), dim3(512), 0, stream>>>(
      xb, wu, cnt, (void*)hbuf);
  // GEMM2: out = float(bf16(h@wd^T)); grid 40 x 8 = 320
  ggf<H_DIM, D_DIM, false><<<dim3(40, D_DIM / 128), dim3(512), 0, stream>>>(
      hbuf, wd, cnt, (void*)out);
}

// Round 15
// 112.358 us; speedup vs baseline: 1.4066x; 1.0856x over previous
//
#include <hip/hip_runtime.h>
#include <stdint.h>

constexpr int T_TOK = 8192;
constexpr int D_DIM = 1024;
constexpr int H_DIM = 2048;
constexpr int E_NUM = 8;

typedef __bf16 bf16x8 __attribute__((ext_vector_type(8)));
typedef float  f32x4  __attribute__((ext_vector_type(4)));

static __device__ __forceinline__ unsigned short f2bf(float f) {
  union { float f; unsigned u; } a; a.f = f;
  unsigned r = a.u + 0x7fffu + ((a.u >> 16) & 1u);   // RNE
  return (unsigned short)(r >> 16);
}

// ---------------- fp32 -> bf16 conversion (x only) ----------------
__global__ void cvt_f32_bf16(const float* __restrict__ src,
                             unsigned short* __restrict__ dst, int n4) {
  int i = blockIdx.x * blockDim.x + threadIdx.x;
  int stride = gridDim.x * blockDim.x;
  for (; i < n4; i += stride) {
    float4 v = reinterpret_cast<const float4*>(src)[i];
    ushort4 o;
    o.x = f2bf(v.x); o.y = f2bf(v.y); o.z = f2bf(v.z); o.w = f2bf(v.w);
    reinterpret_cast<ushort4*>(dst)[i] = o;
  }
}

#define FENCE() asm volatile("" ::: "memory")
#define BARRIER() do { FENCE(); __builtin_amdgcn_s_barrier(); FENCE(); } while (0)
#define WAIT_LGKM0() asm volatile("s_waitcnt lgkmcnt(0)" ::: "memory")
#define WAIT_VM(N) asm volatile("s_waitcnt vmcnt(%0)" :: "i"(N) : "memory")

// ==== tri-buffered BK=32 grouped GEMM; all staging via global_load_lds ====
// A: (T,K) bf16. B: (E,N,K) fp32, converted to bf16 on the LDS-READ side.
// One barrier + one counted WAIT_VM(ISS) per K-step; stages issued 2 steps
// ahead (3 buffers). Per step per wave: 2 A-issues + BI B-issues (1KB each),
// 8+2*NACC ds_read_b128, 8*NACC MFMA between barriers.
//
// Ledger: entering step t's WAIT_VM: outstanding = [t's ISS, t+1's ISS];
// vm(ISS) drains t's batch; BARRIER publishes buf[t%3]; body issues t+2's
// batch into buf[(t+2)%3], whose previous reader (step t-1) completed its
// ds_reads before this same barrier. Single-barrier-per-step is sufficient.
//
// Swizzles (both-sides rule #21 — pre-swizzled global source, XOR on read):
//  A rows = 64B (4 granules):  g ^= (row>>1)&3   -> 2-way on read (free)
//  B rows = 128B (8 granules): g ^= row&7        -> 2-way on read (free)
template <int K_DIM, int N_DIM, int BN, bool RELU2>
__global__ __launch_bounds__(512, 2)
void ggt(const unsigned short* __restrict__ A,
         const float* __restrict__ Bw,
         const int* __restrict__ counts,
         void* __restrict__ Cout) {
  constexpr int BM = 256, BK = 32;
  constexpr int NT = K_DIM / BK;        // 32 (G1) / 64 (G2)
  constexpr int WN = BN / 4;            // 64 / 32
  constexpr int NACC = WN / 16;         // 4 / 2
  constexpr int BI  = BN / 64;          // B issues/wave/step: 4 / 2
  constexpr int ISS = 2 + BI;           // 6 / 4

  const int tid  = threadIdx.x;
  const int wid  = tid >> 6;
  const int lane = tid & 63;
  const int wr   = wid >> 2;            // 0..1
  const int wc   = wid & 3;             // 0..3

  // ---- XCD swizzle: 8 col-tiles pinned per XCD (wg % 8)
  const int id = blockIdx.x + gridDim.x * blockIdx.y;
  const int ct = id & 7;
  const int rt = id >> 3;

  // ---- rt -> (expert, 256-row tile)
  int t = rt;
  int e = -1, rowBase = 0, rowsValid = 0;
  {
    int tiles = 0, off = 0;
#pragma unroll
    for (int i = 0; i < E_NUM; ++i) {
      int n  = counts[i];
      int nt = (n + BM - 1) / BM;
      if (e < 0 && t < tiles + nt) {
        e = i;
        int lt = t - tiles;
        rowBase   = off + lt * BM;
        rowsValid = n - lt * BM;
        if (rowsValid > BM) rowsValid = BM;
      }
      tiles += nt; off += n;
    }
  }
  if (e < 0) return;
  const int colBase = ct * BN;

  // LDS: 3 x (A 16KB + B BN*128B)  -> G1 144 KiB, G2 96 KiB
  __shared__ __align__(1024) char lds[3 * (BM * 64 + BN * 128)];
  auto ldsA = [&](int b) -> char* { return lds + b * (BM * 64); };
  auto ldsB = [&](int b) -> char* { return lds + 3 * (BM * 64) + b * (BN * 128); };

  const char* gA = (const char*)A + (size_t)rowBase * (K_DIM * 2);
  const char* gB = (const char*)Bw + ((size_t)e * N_DIM + colBase) * (size_t)(K_DIM * 4);

  // stage one A K-step slab (256 rows x 64B) : 2 issues/wave
  auto stageA = [&](int buf, int kt) {
#pragma unroll
    for (int j = 0; j < 2; ++j) {
      int row0u = j * 128 + wid * 16;              // wave-uniform
      int r  = row0u + (lane >> 2);
      int sr = (r < rowsValid) ? r : rowsValid - 1;
      int sg = (lane & 3) ^ ((r >> 1) & 3);        // dest-row-based swizzle
      const char* src = gA + (size_t)sr * (K_DIM * 2) + (size_t)kt * 64 + sg * 16;
      __builtin_amdgcn_global_load_lds(
          (const __attribute__((address_space(1))) void*)src,
          (__attribute__((address_space(3))) void*)(ldsA(buf) + row0u * 64),
          16, 0, 0);
    }
  };
  // stage one B K-step slab (BN rows x 128B fp32) : BI issues/wave
  auto stageB = [&](int buf, int kt) {
#pragma unroll
    for (int j = 0; j < BI; ++j) {
      int row0u = j * 64 + wid * 8;
      int r  = row0u + (lane >> 3);
      int sg = (lane & 7) ^ (r & 7);
      const char* src = gB + (size_t)r * (K_DIM * 4) + (size_t)kt * 128 + sg * 16;
      __builtin_amdgcn_global_load_lds(
          (const __attribute__((address_space(1))) void*)src,
          (__attribute__((address_space(3))) void*)(ldsB(buf) + row0u * 128),
          16, 0, 0);
    }
  };

  const int rl = lane & 15;
  const int gh = lane >> 4;             // 0..3

  bf16x8 aF[8], bF[NACC];
  f32x4  accC[8][NACC];
#pragma unroll
  for (int m = 0; m < 8; ++m)
#pragma unroll
    for (int n = 0; n < NACC; ++n) accC[m][n] = (f32x4){0.f, 0.f, 0.f, 0.f};

  auto readA = [&](int buf) {
    const char* base = ldsA(buf);
#pragma unroll
    for (int m = 0; m < 8; ++m) {
      int r = wr * 128 + m * 16 + rl;
      int g = gh ^ ((r >> 1) & 3);
      aF[m] = *(const bf16x8*)(base + r * 64 + g * 16);
    }
  };
  auto readB = [&](int buf) {
    const char* base = ldsB(buf);
#pragma unroll
    for (int n = 0; n < NACC; ++n) {
      int r = wc * WN + n * 16 + rl;
      const char* rb = base + r * 128;
      f32x4 v0 = *(const f32x4*)(rb + (((2 * gh + 0) ^ (r & 7)) * 16));
      f32x4 v1 = *(const f32x4*)(rb + (((2 * gh + 1) ^ (r & 7)) * 16));
      union { __bf16 b[8]; bf16x8 v; } u;
#pragma unroll
      for (int p = 0; p < 4; ++p) {
        u.b[p]     = (__bf16)v0[p];                // v_cvt_pk_bf16_f32
        u.b[4 + p] = (__bf16)v1[p];
      }
      bF[n] = u.v;
    }
  };

  // ---- prologue: issue steps 0 and 1 (2*ISS outstanding); loop drains.
  stageA(0, 0); stageB(0, 0);
  stageA(1, 1); stageB(1, 1);

  for (int t2 = 0; t2 < NT; ++t2) {
    WAIT_VM(ISS);                       // drains step-t2's stages
    BARRIER();                          // publishes buf[t2%3]
    const int ks = (t2 + 2 < NT) ? t2 + 2 : NT - 1;
    const int bs = (t2 + 2) % 3;
    const int bc = t2 % 3;
    stageA(bs, ks);
    stageB(bs, ks);
    readA(bc);
    readB(bc);
    WAIT_LGKM0();
    __builtin_amdgcn_s_setprio(1);
#pragma unroll
    for (int m = 0; m < 8; ++m)
#pragma unroll
      for (int n = 0; n < NACC; ++n)
        accC[m][n] = __builtin_amdgcn_mfma_f32_16x16x32_bf16(
            aF[m], bF[n], accC[m][n], 0, 0, 0);
    __builtin_amdgcn_s_setprio(0);
  }
  WAIT_VM(0);                           // drain tail stages (LDS-only, cheap)

  // ---- epilogue. C/D: col = lane&15, row = (lane>>4)*4 + j
  const int rB0 = wr * 128 + gh * 4;
  const int cB0 = colBase + wc * WN + rl;
#pragma unroll
  for (int m = 0; m < 8; ++m) {
#pragma unroll
    for (int n = 0; n < NACC; ++n) {
#pragma unroll
      for (int j = 0; j < 4; ++j) {
        int r = rB0 + m * 16 + j;
        if (r < rowsValid) {
          size_t idx = (size_t)(rowBase + r) * N_DIM + (cB0 + n * 16);
          float v = accC[m][n][j];
          if (RELU2) {
            float rv = v > 0.f ? v : 0.f;
            float hf = (float)(__bf16)rv;              // bf16(relu(acc))
            ((__bf16*)Cout)[idx] = (__bf16)(hf * hf);  // bf16 square
          } else {
            ((float*)Cout)[idx] = (float)(__bf16)v;    // float(bf16(acc))
          }
        }
      }
    }
  }
}

extern "C" void kernel_launch(void* const* d_in, const int* in_sizes, int n_in,
                              void* d_out, int out_size, void* d_ws, size_t ws_size,
                              hipStream_t stream) {
  const float* x   = (const float*)d_in[0];
  const int*   cnt = (const int*)d_in[1];
  const float* wu  = (const float*)d_in[2];
  const float* wd  = (const float*)d_in[3];
  float* out = (float*)d_out;
  char*  ws  = (char*)d_ws;

  unsigned short* xb   = (unsigned short*)(ws);                // 16 MiB
  unsigned short* hbuf = (unsigned short*)(ws + (16u << 20));  // 32 MiB

  cvt_f32_bf16<<<2048, 256, 0, stream>>>(x, xb, T_TOK * D_DIM / 4);

  // GEMM1: h = bf16(bf16(relu(x@wu^T))^2); BN=256; grid 40x8 (256 working)
  ggt<D_DIM, H_DIM, 256, true ><<<dim3(40, H_DIM / 256), dim3(512), 0, stream>>>(
      xb, wu, cnt, (void*)hbuf);
  // GEMM2: out = float(bf16(h@wd^T)); BN=128; grid 40x8 (256 working)
  ggt<H_DIM, D_DIM, 128, false><<<dim3(40, D_DIM / 128), dim3(512), 0, stream>>>(
      hbuf, wd, cnt, (void*)out);
}